// Round 1
// baseline (71.860 us; speedup 1.0000x reference)
//
#include <hip/hip_runtime.h>

// Embedding gather: out[row, :] = (ids[row] != 0) ? table[ids[row], :] : 0
// rows = 4096*200 = 819200, DIM = 64 f32 -> 16 float4 segments per row.
// Pure memory-bound: ~420 MB total traffic, roofline ~67 us @ 6.3 TB/s.

constexpr int ROWS   = 4096 * 200;       // 819200
constexpr int SEGS   = 16;               // float4 per row (64 floats)
constexpr int TOTAL  = ROWS * SEGS;      // 13,107,200 float4 work units (fits int32)

__global__ __launch_bounds__(256) void embed_gather_kernel(
    const int* __restrict__ ids,
    const float4* __restrict__ table,
    float4* __restrict__ out)
{
    int i      = blockIdx.x * blockDim.x + threadIdx.x;
    int stride = gridDim.x * blockDim.x;

    for (; i < TOTAL; i += stride) {
        int row = i >> 4;        // which embedding row
        int seg = i & 15;        // which float4 within the row
        int id  = ids[row];      // 16 lanes share this -> L1 broadcast

        float4 v;
        if (id != 0) {
            // id < 1e6, *16 + 15 < 2^24 -> int32 indexing is safe
            v = table[id * SEGS + seg];
        } else {
            v = make_float4(0.f, 0.f, 0.f, 0.f);
        }
        out[i] = v;              // consecutive i -> fully coalesced 16B stores
    }
}

extern "C" void kernel_launch(void* const* d_in, const int* in_sizes, int n_in,
                              void* d_out, int out_size, void* d_ws, size_t ws_size,
                              hipStream_t stream)
{
    const int*    ids   = (const int*)d_in[0];
    const float4* table = (const float4*)d_in[1];
    float4*       out   = (float4*)d_out;

    // Memory-bound: cap grid, grid-stride the rest (G11).
    const int block = 256;
    int blocks = (TOTAL + block - 1) / block;      // 51200
    if (blocks > 2048) blocks = 2048;              // ~8 blocks/CU, 25 iters each

    embed_gather_kernel<<<blocks, block, 0, stream>>>(ids, table, out);
}

// Round 2
// 68.502 us; speedup vs baseline: 1.0490x; 1.0490x over previous
//
#include <hip/hip_runtime.h>

// Embedding gather: out[row,:] = (ids[row] != 0) ? table[ids[row],:] : 0
// rows = 819200, DIM = 64 f32 -> 16 float4 per row.
// Memory-bound: ~356 MB effective HBM traffic (L3 absorbs repeat rows),
// floor ~51-55 us @ ~7 TB/s demonstrated. Round-1 (71.9 us) was
// latency-limited: 1 gather in flight per thread. Fix: unroll x5 ILP +
// nontemporal stores (write-once output shouldn't evict table from L2/L3).

typedef float __attribute__((ext_vector_type(4))) f32x4;

constexpr int ROWS       = 4096 * 200;        // 819200
constexpr int SEGS       = 16;                // float4 per row
constexpr int TOTAL      = ROWS * SEGS;       // 13,107,200
constexpr int BLOCK      = 256;
constexpr int BLOCKS     = 2048;              // 8 blocks/CU -> full 32 waves/CU
constexpr int THREADS    = BLOCKS * BLOCK;    // 524288
constexpr int PER_THREAD = TOTAL / THREADS;   // 25
constexpr int UNROLL     = 5;
constexpr int ITERS      = PER_THREAD / UNROLL; // 5
static_assert(TOTAL % THREADS == 0, "exact tiling");
static_assert(PER_THREAD % UNROLL == 0, "exact unroll");

__global__ __launch_bounds__(BLOCK) void embed_gather_kernel(
    const int*   __restrict__ ids,
    const f32x4* __restrict__ table,
    f32x4*       __restrict__ out)
{
    const int tid = blockIdx.x * BLOCK + threadIdx.x;

    for (int it = 0; it < ITERS; ++it) {
        const int base = tid + it * UNROLL * THREADS;

        // Phase 1: issue all 5 id loads (L1/L2-resident, 16 lanes share each)
        int idx[UNROLL], idv[UNROLL];
        #pragma unroll
        for (int k = 0; k < UNROLL; ++k) {
            idx[k] = base + k * THREADS;
            idv[k] = ids[idx[k] >> 4];
        }

        // Phase 2: issue all 5 gathers unconditionally (row 0 is a valid,
        // hot-cached row), select-zero afterwards -> no exec-mask branch,
        // 5 random gathers in flight per wave.
        f32x4 v[UNROLL];
        #pragma unroll
        for (int k = 0; k < UNROLL; ++k) {
            v[k] = table[idv[k] * SEGS + (idx[k] & 15)];
        }
        #pragma unroll
        for (int k = 0; k < UNROLL; ++k) {
            if (idv[k] == 0) v[k] = (f32x4)(0.0f);   // v_cndmask x4
        }

        // Phase 3: coalesced nontemporal 16B stores (don't pollute L2/L3)
        #pragma unroll
        for (int k = 0; k < UNROLL; ++k) {
            __builtin_nontemporal_store(v[k], &out[idx[k]]);
        }
    }
}

extern "C" void kernel_launch(void* const* d_in, const int* in_sizes, int n_in,
                              void* d_out, int out_size, void* d_ws, size_t ws_size,
                              hipStream_t stream)
{
    const int*   ids   = (const int*)d_in[0];
    const f32x4* table = (const f32x4*)d_in[1];
    f32x4*       out   = (f32x4*)d_out;

    embed_gather_kernel<<<BLOCKS, BLOCK, 0, stream>>>(ids, table, out);
}

// Round 3
// 65.140 us; speedup vs baseline: 1.1032x; 1.0516x over previous
//
#include <hip/hip_runtime.h>

// Embedding gather: out[row,:] = (ids[row] != 0) ? table[ids[row],:] : 0
// rows = 819200, DIM = 64 f32 -> 16 float4 per row.
// Round-3 probe: max-TLP one-shot (1 float4 per thread, 51200 blocks,
// no grid-stride loop). Tests whether round-2's 68.5 us was
// parallelism-limited (H1) or DRAM-random-read-efficiency-limited (H2).

typedef float __attribute__((ext_vector_type(4))) f32x4;

constexpr int ROWS   = 4096 * 200;       // 819200
constexpr int SEGS   = 16;               // float4 per row
constexpr int TOTAL  = ROWS * SEGS;      // 13,107,200 threads
constexpr int BLOCK  = 256;
constexpr int BLOCKS = TOTAL / BLOCK;    // 51200, exact
static_assert(TOTAL % BLOCK == 0, "exact tiling");

__global__ __launch_bounds__(BLOCK) void embed_gather_kernel(
    const int*   __restrict__ ids,
    const f32x4* __restrict__ table,
    f32x4*       __restrict__ out)
{
    const int i  = blockIdx.x * BLOCK + threadIdx.x;
    const int id = ids[i >> 4];          // 16 lanes broadcast-share each id

    // Unconditional gather (row 0 valid + hot), branchless zero-select.
    f32x4 v = table[id * SEGS + (i & 15)];
    if (id == 0) v = (f32x4)(0.0f);

    __builtin_nontemporal_store(v, &out[i]);  // coalesced 16B stream store
}

extern "C" void kernel_launch(void* const* d_in, const int* in_sizes, int n_in,
                              void* d_out, int out_size, void* d_ws, size_t ws_size,
                              hipStream_t stream)
{
    const int*   ids   = (const int*)d_in[0];
    const f32x4* table = (const f32x4*)d_in[1];
    f32x4*       out   = (f32x4*)d_out;

    embed_gather_kernel<<<BLOCKS, BLOCK, 0, stream>>>(ids, table, out);
}

// Round 4
// 64.986 us; speedup vs baseline: 1.1058x; 1.0024x over previous
//
#include <hip/hip_runtime.h>

// Embedding gather: out[row,:] = (ids[row] != 0) ? table[ids[row],:] : 0
// rows = 819200, DIM = 64 f32 -> 16 float4 per row; 16 lanes cooperate per
// row, one wave covers 4 rows (4 x 256 B random gather segments/instr).
// Round-4 probe: wave-uniform scalar load of the 4 ids (s_load_dwordx4 via
// readfirstlane) + cndmask select, removing the per-lane ids VMEM load and
// its vmcnt dependency from the gather critical path.
// Traffic floor: 210 MB st + ~143 MB unique-row ld + 3.3 MB ids ~= 356 MB
// -> 56.5 us @ 6.3 TB/s mixed. Round-3 = 65.1 us (~5.5 TB/s effective).

typedef float __attribute__((ext_vector_type(4))) f32x4;

constexpr int ROWS   = 4096 * 200;       // 819200
constexpr int SEGS   = 16;               // float4 per row
constexpr int TOTAL  = ROWS * SEGS;      // 13,107,200 threads
constexpr int BLOCK  = 256;
constexpr int BLOCKS = TOTAL / BLOCK;    // 51200, exact
static_assert(TOTAL % BLOCK == 0, "exact tiling");

__global__ __launch_bounds__(BLOCK) void embed_gather_kernel(
    const int*   __restrict__ ids,
    const f32x4* __restrict__ table,
    f32x4*       __restrict__ out)
{
    const int tid = blockIdx.x * BLOCK + threadIdx.x;

    // Wave-uniform base row (4 consecutive rows per wave, 16 B aligned):
    // lane 0's tid is a multiple of 64 -> tid>>4 is a multiple of 4.
    const int rowBase = __builtin_amdgcn_readfirstlane(tid) >> 4;

    // One scalar 16 B load supplies all 4 ids for the wave (lgkmcnt path,
    // no per-lane VMEM load, no vmcnt ordering vs the gather).
    const int4 ids4 = *reinterpret_cast<const int4*>(ids + rowBase);

    // Per-lane select of this quarter-wave's id: 3 v_cndmask.
    const int quad = (threadIdx.x >> 4) & 3;
    int id = quad == 0 ? ids4.x
           : quad == 1 ? ids4.y
           : quad == 2 ? ids4.z
                       : ids4.w;

    // Unconditional gather (row 0 valid + hot-cached), branchless zero.
    f32x4 v = table[id * SEGS + (tid & 15)];
    if (id == 0) v = (f32x4)(0.0f);

    __builtin_nontemporal_store(v, &out[tid]);  // coalesced 16 B stream store
}

extern "C" void kernel_launch(void* const* d_in, const int* in_sizes, int n_in,
                              void* d_out, int out_size, void* d_ws, size_t ws_size,
                              hipStream_t stream)
{
    const int*   ids   = (const int*)d_in[0];
    const f32x4* table = (const f32x4*)d_in[1];
    f32x4*       out   = (f32x4*)d_out;

    embed_gather_kernel<<<BLOCKS, BLOCK, 0, stream>>>(ids, table, out);
}